// Round 8
// baseline (355.931 us; speedup 1.0000x reference)
//
#include <hip/hip_runtime.h>
#include <cmath>

typedef short short8 __attribute__((ext_vector_type(8)));
typedef float f32x16 __attribute__((ext_vector_type(16)));

#define EPSF 1.1920929e-07f

// ---------------- LDS layout (bytes), total 52224 -> 3 blocks/CU ----------------
#define LDS_XA 0        // [32][24] ush bf16 xA (dead after P1)
#define LDS_X1 1536     // [32][264] ush : A1h, then A2W
#define LDS_X2 18432    // [32][264] ush : A1w (dead after P2w); head overlaid by H32 [32][16] f32
#define LDS_X3 35328    // [32][264] ush : A2H
#define LDS_TOTAL 52224

// ---------------- packed weights (ushort offsets) in d_ws ----------------
// Swapped-operand packing (R6/R7-verified): A-frag lane l holds A'[m=l&31][k=(l>>5)*8+e],
// A'[m][k] = W[kt*16+k][chan(m)]; D reg rr (half q=l>>5) = channel base + q*16 + rr.
#define OFF1H 0        // 8 tiles x 1 kt
#define OFF1W 4096
#define OFF2H 8192     // 8 ct x 16 kt
#define OFF2W 73728
#define OFF3W 139264   // 16 d x 16 kt (chan stride 32)
#define OFF3H 270336   // 16 d x 16 kt (chan stride 33, k=0..31)
#define OFFH32 401408  // 16 kt (16 valid ch: col = rr*33+32, q==0 only)
#define OFFB_BYTES 819200  // float area: hb3 repacked [16][32] + hb32[16]

__device__ __forceinline__ unsigned short f2bf(float f) {   // round-half-up (P0 only)
  union { float f; unsigned u; } v; v.f = f;
  return (unsigned short)((v.u + 0x8000u) >> 16);
}
__device__ __forceinline__ float sp_eps(float v) {          // softplus + EPS
  return fmaxf(v, 0.f) + __logf(1.f + __expf(-fabsf(v))) + EPSF;
}
__device__ __forceinline__ int chanm(int m) {               // (rr,q) channel of A-row m
  return (((m >> 2) & 1) << 4) + (m & 3) + ((m >> 3) << 2);
}
__device__ __forceinline__ unsigned cvtpk(float lo, float hi) {
  unsigned r;
  asm("v_cvt_pk_bf16_f32 %0, %1, %2" : "=v"(r) : "v"(lo), "v"(hi));
  return r;
}

__global__ void pack_weights(const float* __restrict__ hW1, const float* __restrict__ wW1,
                             const float* __restrict__ hW2, const float* __restrict__ wW2,
                             const float* __restrict__ hW3, const float* __restrict__ wW3,
                             const float* __restrict__ hb3,
                             unsigned short* __restrict__ out) {
  int bid = blockIdx.x, l = threadIdx.x;
  if (bid == 800) {     // repack hb3 to stride-32 (aligned float4) + hb32 tail
    float* fb = (float*)((char*)out + OFFB_BYTES);
    for (int idx = l; idx < 528; idx += 64) {
      int d = idx / 33, j = idx - d * 33;
      if (j < 32) fb[d * 32 + j] = hb3[idx];
      else fb[512 + d] = hb3[idx];
    }
    return;
  }
  int m = l & 31;
  const float* W; unsigned short* dst; int tile, col, NC;
  if (bid < 8)        { W = hW1; dst = out + OFF1H;  tile = bid;       col = tile * 32 + chanm(m); NC = 256; }
  else if (bid < 16)  { W = wW1; dst = out + OFF1W;  tile = bid - 8;   col = tile * 32 + chanm(m); NC = 256; }
  else if (bid < 144) { W = hW2; dst = out + OFF2H;  tile = bid - 16;  col = (tile >> 4) * 32 + chanm(m); NC = 256; }
  else if (bid < 272) { W = wW2; dst = out + OFF2W;  tile = bid - 144; col = (tile >> 4) * 32 + chanm(m); NC = 256; }
  else if (bid < 528) { W = wW3; dst = out + OFF3W;  tile = bid - 272; col = (tile >> 4) * 32 + chanm(m); NC = 512; }
  else if (bid < 784) { W = hW3; dst = out + OFF3H;  tile = bid - 528; col = (tile >> 4) * 33 + chanm(m); NC = 528; }
  else {
    W = hW3; dst = out + OFFH32; tile = bid - 784;
    int qq = (m >> 2) & 1, rr = (m & 3) + ((m >> 3) << 2);
    col = qq ? -1 : rr * 33 + 32; NC = 528;
  }
  int kt = (bid < 16) ? 0 : (tile & 15);
  int K  = (bid < 16) ? 16 : 256;
  int k0 = kt * 16 + (l >> 5) * 8;
  short8 v;
  #pragma unroll
  for (int e = 0; e < 8; e++) {
    float f = (col >= 0 && (k0 + e) < K) ? W[(k0 + e) * NC + col] : 0.f;
    v[e] = (short)f2bf(f);
  }
  *(short8*)(dst + (tile * 64 + l) * 8) = v;
}

__device__ __forceinline__ f32x16 bias_init(const float* __restrict__ b) {
  const float4* bp = (const float4*)b;
  float4 b0 = bp[0], b1 = bp[1], b2 = bp[2], b3 = bp[3];
  f32x16 a;
  a[0] = b0.x;  a[1] = b0.y;  a[2] = b0.z;  a[3] = b0.w;
  a[4] = b1.x;  a[5] = b1.y;  a[6] = b1.z;  a[7] = b1.w;
  a[8] = b2.x;  a[9] = b2.y;  a[10] = b2.z; a[11] = b2.w;
  a[12] = b3.x; a[13] = b3.y; a[14] = b3.z; a[15] = b3.w;
  return a;
}

__device__ __forceinline__ void store_act16(unsigned short* dst, f32x16 a) {
  unsigned pk0 = cvtpk(fmaxf(a[0], 0.f),  fmaxf(a[1], 0.f));
  unsigned pk1 = cvtpk(fmaxf(a[2], 0.f),  fmaxf(a[3], 0.f));
  unsigned pk2 = cvtpk(fmaxf(a[4], 0.f),  fmaxf(a[5], 0.f));
  unsigned pk3 = cvtpk(fmaxf(a[6], 0.f),  fmaxf(a[7], 0.f));
  unsigned pk4 = cvtpk(fmaxf(a[8], 0.f),  fmaxf(a[9], 0.f));
  unsigned pk5 = cvtpk(fmaxf(a[10], 0.f), fmaxf(a[11], 0.f));
  unsigned pk6 = cvtpk(fmaxf(a[12], 0.f), fmaxf(a[13], 0.f));
  unsigned pk7 = cvtpk(fmaxf(a[14], 0.f), fmaxf(a[15], 0.f));
  uint4 p0 = {pk0, pk1, pk2, pk3}, p1 = {pk4, pk5, pk6, pk7};
  *(uint4*)dst = p0;
  *(uint4*)(dst + 8) = p1;
}

// one L2-style phase: dst[all rows][ct=w slice] = relu(src @ W + b)
__device__ __forceinline__ void l2_phase(const unsigned short* __restrict__ src,
                                         unsigned short* __restrict__ dst,
                                         const unsigned short* __restrict__ aBase,
                                         const float* __restrict__ bias,
                                         int w, int l, int q, int r32) {
  f32x16 acc = bias_init(bias + w * 32 + q * 16);
  const unsigned short* aB = aBase + w * 16 * 512 + l * 8;
  const unsigned short* bB = src + r32 * 264 + q * 8;
  #pragma unroll
  for (int kt = 0; kt < 16; kt++)
    acc = __builtin_amdgcn_mfma_f32_32x32x16_bf16(*(const short8*)(aB + kt * 512),
                                                  *(const short8*)(bB + kt * 16), acc, 0, 0, 0);
  store_act16(dst + r32 * 264 + w * 32 + q * 16, acc);
}

__device__ __forceinline__ void spline_store(f32x16 e, f32x16 hh, int d, int r32, int q,
                                             const float* __restrict__ H32p,
                                             const float* __restrict__ x,
                                             float* __restrict__ y, int r0) {
  int grow = r0 + r32;
  float se = 0.f;
  #pragma unroll
  for (int k = 0; k < 16; k++) se += e[k];
  float so = __shfl_xor(se, 32);
  float s = se + so;
  float h16o = __shfl_xor(hh[0], 32);            // partner's h[start]
  float hlast = q ? H32p[r32 * 16 + d] : h16o;   // h[32] for q1, h[16] for q0
  float xbv = x[grow * 32 + 2 * d + 1];
  float xbs = xbv * s;
  float bl0 = q ? so : 0.f;
  int fnd = (xbs >= bl0) ? 1 : 0;
  float bl = bl0, cl2 = 0.f, sxl = bl0, sew = e[0], shl = hh[0], shr = hh[1], scl2 = 0.f;
  #pragma unroll
  for (int k = 0; k < 16; k++) {
    float hk = hh[k];
    float hn = (k < 15) ? hh[k + 1] : hlast;
    bool c = (xbs >= bl);
    sxl  = c ? bl   : sxl;
    sew  = c ? e[k] : sew;
    shl  = c ? hk   : shl;
    shr  = c ? hn   : shr;
    scl2 = c ? cl2  : scl2;
    cl2 += (hk + hn) * e[k];
    bl  += e[k];
  }
  float cl2o = __shfl_xor(cl2, 32);
  float S2 = cl2 + cl2o;
  scl2 += q ? cl2o : 0.f;                        // globalize upper half's prefix
  int   o_fnd  = __shfl_xor(fnd, 32);
  float o_sxl  = __shfl_xor(sxl, 32);
  float o_sew  = __shfl_xor(sew, 32);
  float o_shl  = __shfl_xor(shl, 32);
  float o_shr  = __shfl_xor(shr, 32);
  float o_scl2 = __shfl_xor(scl2, 32);
  bool other = q ? (fnd == 0) : (o_fnd != 0);
  float gsxl  = other ? o_sxl  : sxl;
  float gsew  = other ? o_sew  : sew;
  float gshl  = other ? o_shl  : shl;
  float gshr  = other ? o_shr  : shr;
  float gscl2 = other ? o_scl2 : scl2;
  float alpha = (xbs - gsxl) / (gsew + EPSF);
  float yv = (gscl2 + (alpha * alpha * (gshr - gshl) + 2.f * alpha * gshl) * gsew) / S2;
  if (q == 0) y[grow * 32 + 2 * d + 1] = yv;
}

__global__ __launch_bounds__(512, 6) void fused_kernel(
    const float* __restrict__ x,
    const float* __restrict__ hb1, const float* __restrict__ hb2,
    const float* __restrict__ wb1, const float* __restrict__ wb2,
    const float* __restrict__ wb3,
    const unsigned short* __restrict__ pw,
    float* __restrict__ y) {
  extern __shared__ char lds[];
  const int t = threadIdx.x;
  const int w = t >> 6, l = t & 63, q = l >> 5, r32 = l & 31;
  const int r0 = blockIdx.x * 32;

  unsigned short* XA = (unsigned short*)(lds + LDS_XA);
  unsigned short* X1 = (unsigned short*)(lds + LDS_X1);
  unsigned short* X2 = (unsigned short*)(lds + LDS_X2);
  unsigned short* X3 = (unsigned short*)(lds + LDS_X3);

  // ---- P0: load x, emit y even cols, stage xA bf16 [32][24] ----
  if (t < 256) {
    int row = t >> 3, c4 = t & 7;
    float4 v = *(const float4*)(x + (r0 + row) * 32 + c4 * 4);
    y[(r0 + row) * 32 + c4 * 4] = v.x;
    y[(r0 + row) * 32 + c4 * 4 + 2] = v.z;
    unsigned short* xa = XA + row * 24 + c4 * 2;
    xa[0] = f2bf(v.x); xa[1] = f2bf(v.z);
  }
  __syncthreads();

  // ---- P1: L1 both nets (wave w -> channel tile w of each) ----
  {
    short8 bx = *(const short8*)(XA + r32 * 24 + q * 8);
    f32x16 ah = bias_init(hb1 + w * 32 + q * 16);
    ah = __builtin_amdgcn_mfma_f32_32x32x16_bf16(
        *(const short8*)(pw + OFF1H + w * 512 + l * 8), bx, ah, 0, 0, 0);
    store_act16(X1 + r32 * 264 + w * 32 + q * 16, ah);
    f32x16 aw = bias_init(wb1 + w * 32 + q * 16);
    aw = __builtin_amdgcn_mfma_f32_32x32x16_bf16(
        *(const short8*)(pw + OFF1W + w * 512 + l * 8), bx, aw, 0, 0, 0);
    store_act16(X2 + r32 * 264 + w * 32 + q * 16, aw);
  }
  __syncthreads();

  // ---- P2h: A1h(X1) -> A2H(X3) ----
  l2_phase(X1, X3, pw + OFF2H, hb2, w, l, q, r32);
  __syncthreads();
  // ---- P2w: A1w(X2) -> A2W(X1) ----
  l2_phase(X2, X1, pw + OFF2W, wb2, w, l, q, r32);
  __syncthreads();

  // ---- P3: G3 + spline, two passes (d = p*8 + w); e,h stay in registers ----
  const float* pwf = (const float*)((const char*)pw + OFFB_BYTES);
  const float* H32p = (const float*)(lds + LDS_X2);
  #pragma unroll 1
  for (int p = 0; p < 2; p++) {
    const int d = p * 8 + w;
    // e = exp(raw_w)
    f32x16 e = bias_init(wb3 + d * 32 + q * 16);
    {
      const unsigned short* aW = pw + OFF3W + d * 16 * 512 + l * 8;
      const unsigned short* bW = X1 + r32 * 264 + q * 8;
      #pragma unroll
      for (int kt = 0; kt < 16; kt++)
        e = __builtin_amdgcn_mfma_f32_32x32x16_bf16(*(const short8*)(aW + kt * 512),
                                                    *(const short8*)(bW + kt * 16), e, 0, 0, 0);
    }
    #pragma unroll
    for (int rr = 0; rr < 16; rr++) e[rr] = __expf(e[rr]);
    // h = softplus(raw_h)+EPS
    f32x16 hh = bias_init(pwf + d * 32 + q * 16);
    {
      const unsigned short* aH = pw + OFF3H + d * 16 * 512 + l * 8;
      const unsigned short* bH = X3 + r32 * 264 + q * 8;
      #pragma unroll
      for (int kt = 0; kt < 16; kt++)
        hh = __builtin_amdgcn_mfma_f32_32x32x16_bf16(*(const short8*)(aH + kt * 512),
                                                     *(const short8*)(bH + kt * 16), hh, 0, 0, 0);
    }
    #pragma unroll
    for (int rr = 0; rr < 16; rr++) hh[rr] = sp_eps(hh[rr]);
    // h[d][32] tile: wave 7, pass 0 only (straggler is small; 3 blocks/CU smooth it)
    if (p == 0 && w == 7) {
      f32x16 a32;
      #pragma unroll
      for (int rr = 0; rr < 16; rr++) a32[rr] = 0.f;
      const unsigned short* a32p = pw + OFFH32 + l * 8;
      const unsigned short* bH = X3 + r32 * 264 + q * 8;
      #pragma unroll
      for (int kt = 0; kt < 16; kt++)
        a32 = __builtin_amdgcn_mfma_f32_32x32x16_bf16(*(const short8*)(a32p + kt * 512),
                                                      *(const short8*)(bH + kt * 16), a32, 0, 0, 0);
      if (q == 0) {
        float* o = (float*)(lds + LDS_X2) + r32 * 16;
        const float* hb32 = pwf + 512;
        #pragma unroll
        for (int g = 0; g < 4; g++) {
          float4 v;
          v.x = sp_eps(a32[4 * g + 0] + hb32[4 * g + 0]);
          v.y = sp_eps(a32[4 * g + 1] + hb32[4 * g + 1]);
          v.z = sp_eps(a32[4 * g + 2] + hb32[4 * g + 2]);
          v.w = sp_eps(a32[4 * g + 3] + hb32[4 * g + 3]);
          *(float4*)(o + 4 * g) = v;
        }
      }
    }
    if (p == 0) __syncthreads();   // H32 visible before first spline
    spline_store(e, hh, d, r32, q, H32p, x, y, r0);
  }
}

extern "C" void kernel_launch(void* const* d_in, const int* in_sizes, int n_in,
                              void* d_out, int out_size, void* d_ws, size_t ws_size,
                              hipStream_t stream) {
  const float* x   = (const float*)d_in[0];
  const float* hW1 = (const float*)d_in[1];
  const float* hb1 = (const float*)d_in[2];
  const float* hW2 = (const float*)d_in[3];
  const float* hb2 = (const float*)d_in[4];
  const float* hW3 = (const float*)d_in[5];
  const float* hb3 = (const float*)d_in[6];
  const float* wW1 = (const float*)d_in[7];
  const float* wb1 = (const float*)d_in[8];
  const float* wW2 = (const float*)d_in[9];
  const float* wb2 = (const float*)d_in[10];
  const float* wW3 = (const float*)d_in[11];
  const float* wb3 = (const float*)d_in[12];
  unsigned short* pw = (unsigned short*)d_ws;

  pack_weights<<<801, 64, 0, stream>>>(hW1, wW1, hW2, wW2, hW3, wW3, hb3, pw);

  hipFuncSetAttribute((const void*)fused_kernel,
                      hipFuncAttributeMaxDynamicSharedMemorySize, LDS_TOTAL);
  fused_kernel<<<4096, 512, LDS_TOTAL, stream>>>(
      x, hb1, hb2, wb1, wb2, wb3, pw, (float*)d_out);
}

// Round 9
// 200.942 us; speedup vs baseline: 1.7713x; 1.7713x over previous
//
#include <hip/hip_runtime.h>
#include <cmath>

typedef short short8 __attribute__((ext_vector_type(8)));
typedef float f32x16 __attribute__((ext_vector_type(16)));

#define EPSF 1.1920929e-07f

// ---------------- LDS layout (bytes), total 52224 -> 3 blocks/CU ----------------
#define LDS_XA 0        // [32][24] ush bf16 xA (dead after P1)
#define LDS_X1 1536     // [32][264] ush : A1h, then A2W
#define LDS_X2 18432    // [32][264] ush : A1w (dead after P2w); head overlaid by H32 [32][16] f32
#define LDS_X3 35328    // [32][264] ush : A2H
#define LDS_TOTAL 52224

// ---------------- packed weights (ushort offsets) in d_ws ----------------
// Swapped-operand packing (R6/R7/R8-verified): A-frag lane l holds A'[m=l&31][k=(l>>5)*8+e],
// A'[m][k] = W[kt*16+k][chan(m)]; D reg rr (half q=l>>5) = channel base + q*16 + rr.
#define OFF1H 0        // 8 tiles x 1 kt
#define OFF1W 4096
#define OFF2H 8192     // 8 ct x 16 kt
#define OFF2W 73728
#define OFF3W 139264   // 16 d x 16 kt (chan stride 32)
#define OFF3H 270336   // 16 d x 16 kt (chan stride 33, k=0..31)
#define OFFH32 401408  // 16 kt (16 valid ch: col = rr*33+32, q==0 only)
#define OFFB_BYTES 819200  // float area: hb3 repacked [16][32] + hb32[16]

__device__ __forceinline__ unsigned short f2bf(float f) {   // round-half-up (P0 only)
  union { float f; unsigned u; } v; v.f = f;
  return (unsigned short)((v.u + 0x8000u) >> 16);
}
__device__ __forceinline__ float sp_eps(float v) {          // softplus + EPS
  return fmaxf(v, 0.f) + __logf(1.f + __expf(-fabsf(v))) + EPSF;
}
__device__ __forceinline__ int chanm(int m) {               // (rr,q) channel of A-row m
  return (((m >> 2) & 1) << 4) + (m & 3) + ((m >> 3) << 2);
}
__device__ __forceinline__ unsigned cvtpk(float lo, float hi) {
  unsigned r;
  asm("v_cvt_pk_bf16_f32 %0, %1, %2" : "=v"(r) : "v"(lo), "v"(hi));
  return r;
}

__global__ void pack_weights(const float* __restrict__ hW1, const float* __restrict__ wW1,
                             const float* __restrict__ hW2, const float* __restrict__ wW2,
                             const float* __restrict__ hW3, const float* __restrict__ wW3,
                             const float* __restrict__ hb3,
                             unsigned short* __restrict__ out) {
  int bid = blockIdx.x, l = threadIdx.x;
  if (bid == 800) {     // repack hb3 to stride-32 (aligned float4) + hb32 tail
    float* fb = (float*)((char*)out + OFFB_BYTES);
    for (int idx = l; idx < 528; idx += 64) {
      int d = idx / 33, j = idx - d * 33;
      if (j < 32) fb[d * 32 + j] = hb3[idx];
      else fb[512 + d] = hb3[idx];
    }
    return;
  }
  int m = l & 31;
  const float* W; unsigned short* dst; int tile, col, NC;
  if (bid < 8)        { W = hW1; dst = out + OFF1H;  tile = bid;       col = tile * 32 + chanm(m); NC = 256; }
  else if (bid < 16)  { W = wW1; dst = out + OFF1W;  tile = bid - 8;   col = tile * 32 + chanm(m); NC = 256; }
  else if (bid < 144) { W = hW2; dst = out + OFF2H;  tile = bid - 16;  col = (tile >> 4) * 32 + chanm(m); NC = 256; }
  else if (bid < 272) { W = wW2; dst = out + OFF2W;  tile = bid - 144; col = (tile >> 4) * 32 + chanm(m); NC = 256; }
  else if (bid < 528) { W = wW3; dst = out + OFF3W;  tile = bid - 272; col = (tile >> 4) * 32 + chanm(m); NC = 512; }
  else if (bid < 784) { W = hW3; dst = out + OFF3H;  tile = bid - 528; col = (tile >> 4) * 33 + chanm(m); NC = 528; }
  else {
    W = hW3; dst = out + OFFH32; tile = bid - 784;
    int qq = (m >> 2) & 1, rr = (m & 3) + ((m >> 3) << 2);
    col = qq ? -1 : rr * 33 + 32; NC = 528;
  }
  int kt = (bid < 16) ? 0 : (tile & 15);
  int K  = (bid < 16) ? 16 : 256;
  int k0 = kt * 16 + (l >> 5) * 8;
  short8 v;
  #pragma unroll
  for (int e = 0; e < 8; e++) {
    float f = (col >= 0 && (k0 + e) < K) ? W[(k0 + e) * NC + col] : 0.f;
    v[e] = (short)f2bf(f);
  }
  *(short8*)(dst + (tile * 64 + l) * 8) = v;
}

__device__ __forceinline__ f32x16 bias_init(const float* __restrict__ b) {
  const float4* bp = (const float4*)b;
  float4 b0 = bp[0], b1 = bp[1], b2 = bp[2], b3 = bp[3];
  f32x16 a;
  a[0] = b0.x;  a[1] = b0.y;  a[2] = b0.z;  a[3] = b0.w;
  a[4] = b1.x;  a[5] = b1.y;  a[6] = b1.z;  a[7] = b1.w;
  a[8] = b2.x;  a[9] = b2.y;  a[10] = b2.z; a[11] = b2.w;
  a[12] = b3.x; a[13] = b3.y; a[14] = b3.z; a[15] = b3.w;
  return a;
}

__device__ __forceinline__ void store_act16(unsigned short* dst, f32x16 a) {
  unsigned pk0 = cvtpk(fmaxf(a[0], 0.f),  fmaxf(a[1], 0.f));
  unsigned pk1 = cvtpk(fmaxf(a[2], 0.f),  fmaxf(a[3], 0.f));
  unsigned pk2 = cvtpk(fmaxf(a[4], 0.f),  fmaxf(a[5], 0.f));
  unsigned pk3 = cvtpk(fmaxf(a[6], 0.f),  fmaxf(a[7], 0.f));
  unsigned pk4 = cvtpk(fmaxf(a[8], 0.f),  fmaxf(a[9], 0.f));
  unsigned pk5 = cvtpk(fmaxf(a[10], 0.f), fmaxf(a[11], 0.f));
  unsigned pk6 = cvtpk(fmaxf(a[12], 0.f), fmaxf(a[13], 0.f));
  unsigned pk7 = cvtpk(fmaxf(a[14], 0.f), fmaxf(a[15], 0.f));
  uint4 p0 = {pk0, pk1, pk2, pk3}, p1 = {pk4, pk5, pk6, pk7};
  *(uint4*)dst = p0;
  *(uint4*)(dst + 8) = p1;
}

// one L2-style phase: dst[all rows][ct=w slice] = relu(src @ W + b)
__device__ __forceinline__ void l2_phase(const unsigned short* __restrict__ src,
                                         unsigned short* __restrict__ dst,
                                         const unsigned short* __restrict__ aBase,
                                         const float* __restrict__ bias,
                                         int w, int l, int q, int r32) {
  f32x16 acc = bias_init(bias + w * 32 + q * 16);
  const unsigned short* aB = aBase + w * 16 * 512 + l * 8;
  const unsigned short* bB = src + r32 * 264 + q * 8;
  #pragma unroll
  for (int kt = 0; kt < 16; kt++)
    acc = __builtin_amdgcn_mfma_f32_32x32x16_bf16(*(const short8*)(aB + kt * 512),
                                                  *(const short8*)(bB + kt * 16), acc, 0, 0, 0);
  store_act16(dst + r32 * 264 + w * 32 + q * 16, acc);
}

__device__ __forceinline__ void spline_store(f32x16 e, f32x16 hh, int d, int r32, int q,
                                             const float* __restrict__ H32p,
                                             const float* __restrict__ x,
                                             float* __restrict__ y, int r0) {
  int grow = r0 + r32;
  float se = 0.f;
  #pragma unroll
  for (int k = 0; k < 16; k++) se += e[k];
  float so = __shfl_xor(se, 32);
  float s = se + so;
  float h16o = __shfl_xor(hh[0], 32);            // partner's h[start]
  float hlast = q ? H32p[r32 * 16 + d] : h16o;   // h[32] for q1, h[16] for q0
  float xbv = x[grow * 32 + 2 * d + 1];
  float xbs = xbv * s;
  float bl0 = q ? so : 0.f;
  int fnd = (xbs >= bl0) ? 1 : 0;
  float bl = bl0, cl2 = 0.f, sxl = bl0, sew = e[0], shl = hh[0], shr = hh[1], scl2 = 0.f;
  #pragma unroll
  for (int k = 0; k < 16; k++) {
    float hk = hh[k];
    float hn = (k < 15) ? hh[k + 1] : hlast;
    bool c = (xbs >= bl);
    sxl  = c ? bl   : sxl;
    sew  = c ? e[k] : sew;
    shl  = c ? hk   : shl;
    shr  = c ? hn   : shr;
    scl2 = c ? cl2  : scl2;
    cl2 += (hk + hn) * e[k];
    bl  += e[k];
  }
  float cl2o = __shfl_xor(cl2, 32);
  float S2 = cl2 + cl2o;
  scl2 += q ? cl2o : 0.f;                        // globalize upper half's prefix
  int   o_fnd  = __shfl_xor(fnd, 32);
  float o_sxl  = __shfl_xor(sxl, 32);
  float o_sew  = __shfl_xor(sew, 32);
  float o_shl  = __shfl_xor(shl, 32);
  float o_shr  = __shfl_xor(shr, 32);
  float o_scl2 = __shfl_xor(scl2, 32);
  bool other = q ? (fnd == 0) : (o_fnd != 0);
  float gsxl  = other ? o_sxl  : sxl;
  float gsew  = other ? o_sew  : sew;
  float gshl  = other ? o_shl  : shl;
  float gshr  = other ? o_shr  : shr;
  float gscl2 = other ? o_scl2 : scl2;
  float alpha = (xbs - gsxl) / (gsew + EPSF);
  float yv = (gscl2 + (alpha * alpha * (gshr - gshl) + 2.f * alpha * gshl) * gsew) / S2;
  if (q == 0) y[grow * 32 + 2 * d + 1] = yv;
}

// NOTE: __launch_bounds__ 2nd arg behaves as min BLOCKS/CU on this toolchain
// (R8 evidence: (512,6) -> VGPR cap ~42 + catastrophic spill). 3 blocks x 512
// threads = 24 waves/CU, VGPR cap ~85.
__global__ __launch_bounds__(512, 3) void fused_kernel(
    const float* __restrict__ x,
    const float* __restrict__ hb1, const float* __restrict__ hb2,
    const float* __restrict__ wb1, const float* __restrict__ wb2,
    const float* __restrict__ wb3,
    const unsigned short* __restrict__ pw,
    float* __restrict__ y) {
  extern __shared__ char lds[];
  const int t = threadIdx.x;
  const int w = t >> 6, l = t & 63, q = l >> 5, r32 = l & 31;
  const int r0 = blockIdx.x * 32;

  unsigned short* XA = (unsigned short*)(lds + LDS_XA);
  unsigned short* X1 = (unsigned short*)(lds + LDS_X1);
  unsigned short* X2 = (unsigned short*)(lds + LDS_X2);
  unsigned short* X3 = (unsigned short*)(lds + LDS_X3);
  const float* pwf = (const float*)((const char*)pw + OFFB_BYTES);

  // ---- P0: load x, emit y even cols, stage xA bf16 [32][24] ----
  if (t < 256) {
    int row = t >> 3, c4 = t & 7;
    float4 v = *(const float4*)(x + (r0 + row) * 32 + c4 * 4);
    y[(r0 + row) * 32 + c4 * 4] = v.x;
    y[(r0 + row) * 32 + c4 * 4 + 2] = v.z;
    unsigned short* xa = XA + row * 24 + c4 * 2;
    xa[0] = f2bf(v.x); xa[1] = f2bf(v.z);
  }
  __syncthreads();

  // ---- P1: L1 both nets (wave w -> channel tile w of each) ----
  {
    short8 bx = *(const short8*)(XA + r32 * 24 + q * 8);
    f32x16 ah = bias_init(hb1 + w * 32 + q * 16);
    ah = __builtin_amdgcn_mfma_f32_32x32x16_bf16(
        *(const short8*)(pw + OFF1H + w * 512 + l * 8), bx, ah, 0, 0, 0);
    store_act16(X1 + r32 * 264 + w * 32 + q * 16, ah);
    f32x16 aw = bias_init(wb1 + w * 32 + q * 16);
    aw = __builtin_amdgcn_mfma_f32_32x32x16_bf16(
        *(const short8*)(pw + OFF1W + w * 512 + l * 8), bx, aw, 0, 0, 0);
    store_act16(X2 + r32 * 264 + w * 32 + q * 16, aw);
  }
  __syncthreads();

  // ---- P2h: A1h(X1) -> A2H(X3) ----
  l2_phase(X1, X3, pw + OFF2H, hb2, w, l, q, r32);
  __syncthreads();

  // ---- P2w: A1w(X2) -> A2W(X1); wave 0 additionally computes h[.][32] ----
  f32x16 a32;
  if (w == 0) {
    #pragma unroll
    for (int rr = 0; rr < 16; rr++) a32[rr] = 0.f;
    const unsigned short* a32p = pw + OFFH32 + l * 8;
    const unsigned short* bH = X3 + r32 * 264 + q * 8;
    #pragma unroll
    for (int kt = 0; kt < 16; kt++)
      a32 = __builtin_amdgcn_mfma_f32_32x32x16_bf16(*(const short8*)(a32p + kt * 512),
                                                    *(const short8*)(bH + kt * 16), a32, 0, 0, 0);
  }
  l2_phase(X2, X1, pw + OFF2W, wb2, w, l, q, r32);
  __syncthreads();

  // X2 (A1w) now dead: wave 0 stores H32 into its head (visible after p==0 barrier)
  if (w == 0 && q == 0) {
    float* o = (float*)(lds + LDS_X2) + r32 * 16;
    const float* hb32 = pwf + 512;
    #pragma unroll
    for (int g = 0; g < 4; g++) {
      float4 v;
      v.x = sp_eps(a32[4 * g + 0] + hb32[4 * g + 0]);
      v.y = sp_eps(a32[4 * g + 1] + hb32[4 * g + 1]);
      v.z = sp_eps(a32[4 * g + 2] + hb32[4 * g + 2]);
      v.w = sp_eps(a32[4 * g + 3] + hb32[4 * g + 3]);
      *(float4*)(o + 4 * g) = v;
    }
  }

  // ---- P3: G3 + spline, two passes (d = p*8 + w); e,h stay in registers ----
  const float* H32p = (const float*)(lds + LDS_X2);
  #pragma unroll 1
  for (int p = 0; p < 2; p++) {
    const int d = p * 8 + w;
    // e = exp(raw_w)
    f32x16 e = bias_init(wb3 + d * 32 + q * 16);
    {
      const unsigned short* aW = pw + OFF3W + d * 16 * 512 + l * 8;
      const unsigned short* bW = X1 + r32 * 264 + q * 8;
      #pragma unroll
      for (int kt = 0; kt < 16; kt++)
        e = __builtin_amdgcn_mfma_f32_32x32x16_bf16(*(const short8*)(aW + kt * 512),
                                                    *(const short8*)(bW + kt * 16), e, 0, 0, 0);
    }
    #pragma unroll
    for (int rr = 0; rr < 16; rr++) e[rr] = __expf(e[rr]);
    // h = softplus(raw_h)+EPS
    f32x16 hh = bias_init(pwf + d * 32 + q * 16);
    {
      const unsigned short* aH = pw + OFF3H + d * 16 * 512 + l * 8;
      const unsigned short* bH = X3 + r32 * 264 + q * 8;
      #pragma unroll
      for (int kt = 0; kt < 16; kt++)
        hh = __builtin_amdgcn_mfma_f32_32x32x16_bf16(*(const short8*)(aH + kt * 512),
                                                     *(const short8*)(bH + kt * 16), hh, 0, 0, 0);
    }
    #pragma unroll
    for (int rr = 0; rr < 16; rr++) hh[rr] = sp_eps(hh[rr]);
    if (p == 0) __syncthreads();   // H32 visible before first spline read
    spline_store(e, hh, d, r32, q, H32p, x, y, r0);
  }
}

extern "C" void kernel_launch(void* const* d_in, const int* in_sizes, int n_in,
                              void* d_out, int out_size, void* d_ws, size_t ws_size,
                              hipStream_t stream) {
  const float* x   = (const float*)d_in[0];
  const float* hW1 = (const float*)d_in[1];
  const float* hb1 = (const float*)d_in[2];
  const float* hW2 = (const float*)d_in[3];
  const float* hb2 = (const float*)d_in[4];
  const float* hW3 = (const float*)d_in[5];
  const float* hb3 = (const float*)d_in[6];
  const float* wW1 = (const float*)d_in[7];
  const float* wb1 = (const float*)d_in[8];
  const float* wW2 = (const float*)d_in[9];
  const float* wb2 = (const float*)d_in[10];
  const float* wW3 = (const float*)d_in[11];
  const float* wb3 = (const float*)d_in[12];
  unsigned short* pw = (unsigned short*)d_ws;

  pack_weights<<<801, 64, 0, stream>>>(hW1, wW1, hW2, wW2, hW3, wW3, hb3, pw);

  hipFuncSetAttribute((const void*)fused_kernel,
                      hipFuncAttributeMaxDynamicSharedMemorySize, LDS_TOTAL);
  fused_kernel<<<4096, 512, LDS_TOTAL, stream>>>(
      x, hb1, hb2, wb1, wb2, wb3, pw, (float*)d_out);
}